// Round 13
// baseline (198.254 us; speedup 1.0000x reference)
//
#include <hip/hip_runtime.h>

#define SEQ  4096
#define DMODEL 1024
#define QTOT 16384           // B*S
#define QSCALE 0.18033688011112042f   // (1/sqrt(64)) * log2(e), folded into Q

typedef __bf16 bf16x8 __attribute__((ext_vector_type(8)));
typedef unsigned short u16x8 __attribute__((ext_vector_type(8)));
typedef float f32x4 __attribute__((ext_vector_type(4)));

// ---------- helpers ----------
static __device__ __forceinline__ unsigned short f2bfbits(float f) {
    unsigned int u = __builtin_bit_cast(unsigned int, f);
    unsigned int lsb = (u >> 16) & 1u;
    u += 0x7fffu + lsb;                      // round-to-nearest-even
    return (unsigned short)(u >> 16);
}

static __device__ __forceinline__ bf16x8 ld_frag(const unsigned short* p) {
    uint4 u = *reinterpret_cast<const uint4*>(p);
    return __builtin_bit_cast(bf16x8, u);
}

// ---------- kernel 1: weights -> bf16, pre-swizzled into MFMA fragment order ----------
__global__ void prep_weights(const float* __restrict__ Wq,
                             const float* __restrict__ Wk,
                             const float* __restrict__ Wv,
                             unsigned short* __restrict__ WtS) {
    int o = blockIdx.x * 256 + threadIdx.x;      // 192*1024 total
    int f = o >> 9, q = o & 511;
    int lane = q >> 3, j = q & 7;
    int kc = f / 12, nt = f - kc * 12;
    int n = nt * 16 + (lane & 15);
    int k = kc * 32 + (lane >> 4) * 8 + j;
    float v;
    if (n < 64)       v = Wq[k * 64 + n];
    else if (n < 128) v = Wk[k * 64 + (n - 64)];
    else              v = Wv[k * 64 + (n - 128)];
    WtS[o] = f2bfbits(v);
}

// ---------- kernel 2: QKV projection, coalesced LDS-staged emb ----------
// (round-3 verified kernel, unchanged. Fragment-ordered K/V outputs were
//  HW-bisected in rounds 8/10 and are wrong despite passing static audit;
//  swapped-QK/cvt_pk softmax was HW-refuted in round 12. Data paths here and
//  in attn are frozen to the verified forms — scheduling-only changes allowed.)
__global__ __launch_bounds__(256) void proj_cs(
        const float* __restrict__ emb, const unsigned short* __restrict__ WtS,
        const float* __restrict__ bq, const float* __restrict__ bk,
        const float* __restrict__ bv,
        unsigned short* __restrict__ Qb, unsigned short* __restrict__ Kb,
        unsigned short* __restrict__ VT) {
    __shared__ __align__(16) unsigned short Et[2][32 * 256];   // 2 x 16 KB

    const int tid = threadIdx.x;
    const int w = tid >> 6, lane = tid & 63;
    const int c = lane & 15, qd = lane >> 4;
    const int m = w & 1, nh = w >> 1;
    const int mbase = blockIdx.x * 32;

    f32x4 acc[6];
#pragma unroll
    for (int i = 0; i < 6; i++) acc[i] = (f32x4){0.f, 0.f, 0.f, 0.f};

    const unsigned short* wpB = WtS + nh * 3072 + lane * 8;

    {
        float4 g[8];
#pragma unroll
        for (int rr = 0; rr < 8; rr++)
            g[rr] = *reinterpret_cast<const float4*>(
                emb + (size_t)(mbase + w * 8 + rr) * DMODEL + lane * 4);
#pragma unroll
        for (int rr = 0; rr < 8; rr++) {
            int row = w * 8 + rr;
            ushort4 p;
            p.x = f2bfbits(g[rr].x); p.y = f2bfbits(g[rr].y);
            p.z = f2bfbits(g[rr].z); p.w = f2bfbits(g[rr].w);
            int off = (lane * 8) ^ ((row & 7) << 4);           // byte off in 512B row
            *reinterpret_cast<ushort4*>(
                reinterpret_cast<char*>(&Et[0][0]) + row * 512 + off) = p;
        }
    }

    bf16x8 wc[6];
#pragma unroll
    for (int jj = 0; jj < 6; jj++) wc[jj] = ld_frag(wpB + jj * 512);

    __syncthreads();

    int cur = 0;
    for (int mega = 0; mega < 4; mega++) {
        float4 g[8];
        if (mega < 3) {
#pragma unroll
            for (int rr = 0; rr < 8; rr++)
                g[rr] = *reinterpret_cast<const float4*>(
                    emb + (size_t)(mbase + w * 8 + rr) * DMODEL
                        + (mega + 1) * 256 + lane * 4);
        }

        const char* Eb = reinterpret_cast<const char*>(&Et[cur][0]);
        bf16x8 aq[8];
#pragma unroll
        for (int ks = 0; ks < 8; ks++) {
            int off = (ks * 64 + qd * 16) ^ ((c & 7) << 4);
            aq[ks] = ld_frag(reinterpret_cast<const unsigned short*>(
                Eb + (m * 16 + c) * 512 + off));
        }

#pragma unroll
        for (int ks = 0; ks < 8; ks++) {
            int s = mega * 8 + ks;
            bf16x8 wn[6];
            if (s < 31) {
#pragma unroll
                for (int jj = 0; jj < 6; jj++)
                    wn[jj] = ld_frag(wpB + (s + 1) * 6144 + jj * 512);
            } else {
#pragma unroll
                for (int jj = 0; jj < 6; jj++) wn[jj] = wc[jj];
            }
#pragma unroll
            for (int jj = 0; jj < 6; jj++)
                acc[jj] = __builtin_amdgcn_mfma_f32_16x16x32_bf16(aq[ks], wc[jj], acc[jj], 0, 0, 0);
#pragma unroll
            for (int jj = 0; jj < 6; jj++) wc[jj] = wn[jj];
        }

        if (mega < 3) {
#pragma unroll
            for (int rr = 0; rr < 8; rr++) {
                int row = w * 8 + rr;
                ushort4 p;
                p.x = f2bfbits(g[rr].x); p.y = f2bfbits(g[rr].y);
                p.z = f2bfbits(g[rr].z); p.w = f2bfbits(g[rr].w);
                int off = (lane * 8) ^ ((row & 7) << 4);
                *reinterpret_cast<ushort4*>(
                    reinterpret_cast<char*>(&Et[cur ^ 1][0]) + row * 512 + off) = p;
            }
        }
        __syncthreads();
        cur ^= 1;
    }

    // ---- epilogue: bias + scale + bf16 store ----
#pragma unroll
    for (int jj = 0; jj < 6; jj++) {
        int n = (nh * 6 + jj) * 16 + c;
        float bias = (n < 64) ? bq[n] : (n < 128) ? bk[n - 64] : bv[n - 128];
        float fac = (n < 64) ? QSCALE : 1.0f;
#pragma unroll
        for (int r = 0; r < 4; r++) {
            int token = mbase + m * 16 + qd * 4 + r;
            unsigned short bits = f2bfbits((acc[jj][r] + bias) * fac);
            if (n < 64)        Qb[(size_t)token * 64 + n] = bits;
            else if (n < 128)  Kb[(size_t)token * 64 + (n - 64)] = bits;
            else {
                int bb = token >> 12, ss = token & 4095;
                VT[((size_t)bb * 64 + (n - 128)) * SEQ + ss] = bits;
            }
        }
    }
}

// ---------- kernel 3: barrier-free flash attention ----------
// round-11 verified body BYTE-FOR-BYTE on the data path (mfma(Q,K) order,
// f2bfbits P-writes, same LDS addresses, 4-shuffle lsum reduce, V-hoist,
// setprio) + ONE scheduling-only change: K double-buffer — iteration i+1's
// K fragments prefetch into separate named registers right after iteration
// i's QK MFMA cluster, so the L2 K-load wait (~200-400cy, head of the serial
// chain at 2 waves/SIMD) overlaps softmax VALU + PV MFMA.
// Single-variable test: round 12 bundled this with a data-path change and
// failed; if this passes (absmax must be exactly 4.882812e-4), the data-path
// change was the bug. If this fails, K-dbuf is guilty -> revert to round 11.
__global__ __launch_bounds__(512, 2) void attn(
        const unsigned short* __restrict__ Qb, const unsigned short* __restrict__ Kb,
        const unsigned short* __restrict__ VT, float* __restrict__ out) {
    __shared__ __align__(16) unsigned short Pl[8][64 * 72];  // per-wave P [q][t]; aliased as reduce buf
    __shared__ float l_all[8][64];

    const int tid = threadIdx.x;
    const int w = tid >> 6, lane = tid & 63;
    const int c = lane & 15, qd = lane >> 4;
    // XCD pinning: blockIdx%8 = b*2 + (qblk&1)
    const int g3 = blockIdx.x & 7;
    const int b = g3 >> 1;
    const int qblk = ((blockIdx.x >> 3) << 1) | (g3 & 1);
    const int qbase = qblk * 64;
    const int tstart = w * 512;

    // Q A-fragments (same for all 8 waves -> L1 broadcast), pre-scaled by QSCALE
    bf16x8 aq0[4], aq1[4];
#pragma unroll
    for (int qs = 0; qs < 4; qs++) {
        const unsigned short* Qp = Qb + ((size_t)(b << 12) + qbase + qs * 16 + c) * 64 + qd * 8;
        aq0[qs] = ld_frag(Qp);
        aq1[qs] = ld_frag(Qp + 32);
    }

    f32x4 acc[16];                               // [qsub][nt]
#pragma unroll
    for (int i = 0; i < 16; i++) acc[i] = (f32x4){0.f, 0.f, 0.f, 0.f};
    float lsum[4][4];                            // [qsub][r] per-lane partial
#pragma unroll
    for (int qs = 0; qs < 4; qs++)
#pragma unroll
        for (int r = 0; r < 4; r++) lsum[qs][r] = 0.f;

    unsigned short* myP = &Pl[w][0];
    const unsigned short* KbB = Kb + (size_t)(b << 12) * 64;

#define LOADK(K0, K1, T0) do {                                               \
        const unsigned short* Kt_ = KbB + (size_t)(T0) * 64;                 \
        _Pragma("unroll")                                                    \
        for (int ts = 0; ts < 4; ts++) {                                     \
            K0[ts] = ld_frag(Kt_ + (ts * 16 + c) * 64 + qd * 8);             \
            K1[ts] = ld_frag(Kt_ + (ts * 16 + c) * 64 + 32 + qd * 8);        \
        } } while (0)

#define ATTN_STEP(T0, CK0, CK1, PF, NK0, NK1, NT0) do {                      \
        const int t0_ = (T0);                                                \
        /* V-fragments issued EARLY (round-11 verified V-hoist) */           \
        bf16x8 bv0_[4], bv1_[4];                                             \
        _Pragma("unroll")                                                    \
        for (int nt = 0; nt < 4; nt++) {                                     \
            const unsigned short* Vp_ =                                      \
                VT + (((size_t)b * 64 + nt * 16 + c) << 12) + t0_ + qd * 8;  \
            bv0_[nt] = ld_frag(Vp_);                                         \
            bv1_[nt] = ld_frag(Vp_ + 32);                                    \
        }                                                                    \
        /* scores -> exp2 -> P into per-wave LDS (round-11 data path) */     \
        _Pragma("unroll")                                                    \
        for (int qs = 0; qs < 4; qs++) {                                     \
            f32x4 sc_[4];                                                    \
            __builtin_amdgcn_s_setprio(1);                                   \
            _Pragma("unroll")                                                \
            for (int ts = 0; ts < 4; ts++) {                                 \
                f32x4 z_ = (f32x4){0.f, 0.f, 0.f, 0.f};                      \
                z_ = __builtin_amdgcn_mfma_f32_16x16x32_bf16(aq0[qs], CK0[ts], z_, 0, 0, 0); \
                z_ = __builtin_amdgcn_mfma_f32_16x16x32_bf16(aq1[qs], CK1[ts], z_, 0, 0, 0); \
                sc_[ts] = z_;                                                \
            }                                                                \
            __builtin_amdgcn_s_setprio(0);                                   \
            /* scheduling-only: prefetch next K tile into the OTHER bufs */  \
            if (qs == 0 && (PF)) { LOADK(NK0, NK1, NT0); }                   \
            _Pragma("unroll")                                                \
            for (int ts = 0; ts < 4; ts++)                                   \
                _Pragma("unroll")                                            \
                for (int r = 0; r < 4; r++) {                                \
                    float p_ = __builtin_amdgcn_exp2f(sc_[ts][r]);           \
                    lsum[qs][r] += p_;                                       \
                    myP[(qs * 16 + qd * 4 + r) * 72 + ts * 16 + c] = f2bfbits(p_); \
                }                                                            \
        }                                                                    \
        /* P A-fragments (same-wave LDS readback) -> PV */                   \
        _Pragma("unroll")                                                    \
        for (int qs = 0; qs < 4; qs++) {                                     \
            bf16x8 ap0_ = ld_frag(&myP[(qs * 16 + c) * 72 + qd * 8]);        \
            bf16x8 ap1_ = ld_frag(&myP[(qs * 16 + c) * 72 + 32 + qd * 8]);   \
            __builtin_amdgcn_s_setprio(1);                                   \
            _Pragma("unroll")                                                \
            for (int nt = 0; nt < 4; nt++) {                                 \
                acc[qs * 4 + nt] = __builtin_amdgcn_mfma_f32_16x16x32_bf16(ap0_, bv0_[nt], acc[qs * 4 + nt], 0, 0, 0); \
                acc[qs * 4 + nt] = __builtin_amdgcn_mfma_f32_16x16x32_bf16(ap1_, bv1_[nt], acc[qs * 4 + nt], 0, 0, 0); \
            }                                                                \
            __builtin_amdgcn_s_setprio(0);                                   \
        }                                                                    \
    } while (0)

    bf16x8 ka0[4], ka1[4], kb0[4], kb1[4];
    LOADK(ka0, ka1, tstart);
    for (int ip = 0; ip < 4; ip++) {
        const int t0 = tstart + ip * 128;
        ATTN_STEP(t0,      ka0, ka1, 1,        kb0, kb1, t0 + 64);
        ATTN_STEP(t0 + 64, kb0, kb1, (ip < 3), ka0, ka1, t0 + 128);
    }
#undef ATTN_STEP
#undef LOADK

    // per-wave row-sum reduction across the 16 column lanes (round-11 verbatim)
#pragma unroll
    for (int off = 1; off < 16; off <<= 1)
#pragma unroll
        for (int qs = 0; qs < 4; qs++)
#pragma unroll
            for (int r = 0; r < 4; r++) lsum[qs][r] += __shfl_xor(lsum[qs][r], off);
    if (c == 0) {
#pragma unroll
        for (int qs = 0; qs < 4; qs++)
#pragma unroll
            for (int r = 0; r < 4; r++)
                l_all[w][qs * 16 + qd * 4 + r] = lsum[qs][r];
    }

    // tree-reduce acc over 8 waves; reduce buffer aliases Pl (slot = 17408 B)
    float* red = (float*)&Pl[0][0];
    __syncthreads();                              // all main loops + l writes done
    if (w >= 4) {
        float* rp = red + (w - 4) * 4352 + lane * 68;
#pragma unroll
        for (int i = 0; i < 16; i++) *reinterpret_cast<f32x4*>(rp + i * 4) = acc[i];
    }
    __syncthreads();
    if (w < 4) {
        float* rp = red + w * 4352 + lane * 68;
#pragma unroll
        for (int i = 0; i < 16; i++) acc[i] += *reinterpret_cast<const f32x4*>(rp + i * 4);
    }
    __syncthreads();
    if (w == 2 || w == 3) {
        float* rp = red + (w - 2) * 4352 + lane * 68;
#pragma unroll
        for (int i = 0; i < 16; i++) *reinterpret_cast<f32x4*>(rp + i * 4) = acc[i];
    }
    __syncthreads();
    if (w < 2) {
        float* rp = red + w * 4352 + lane * 68;
#pragma unroll
        for (int i = 0; i < 16; i++) acc[i] += *reinterpret_cast<const f32x4*>(rp + i * 4);
    }
    __syncthreads();
    if (w == 1) {
        float* rp = red + lane * 68;
#pragma unroll
        for (int i = 0; i < 16; i++) *reinterpret_cast<f32x4*>(rp + i * 4) = acc[i];
    }
    __syncthreads();
    if (w == 0) {
        float* rp = red + lane * 68;
#pragma unroll
        for (int i = 0; i < 16; i++) acc[i] += *reinterpret_cast<const f32x4*>(rp + i * 4);
#pragma unroll
        for (int qs = 0; qs < 4; qs++)
#pragma unroll
            for (int r = 0; r < 4; r++) {
                int q = qs * 16 + qd * 4 + r;
                float l = 0.f;
#pragma unroll
                for (int ww = 0; ww < 8; ww++) l += l_all[ww][q];
                float inv = 1.0f / l;
                size_t row = (size_t)(b << 12) + qbase + q;
#pragma unroll
                for (int nt = 0; nt < 4; nt++)
                    out[row * 64 + nt * 16 + c] = acc[qs * 4 + nt][r] * inv;
            }
    }
}

// ---------- launch ----------
extern "C" void kernel_launch(void* const* d_in, const int* in_sizes, int n_in,
                              void* d_out, int out_size, void* d_ws, size_t ws_size,
                              hipStream_t stream) {
    const float* emb = (const float*)d_in[0];
    const float* Wq  = (const float*)d_in[1];
    const float* bq  = (const float*)d_in[2];
    const float* Wk  = (const float*)d_in[3];
    const float* bk  = (const float*)d_in[4];
    const float* Wv  = (const float*)d_in[5];
    const float* bv  = (const float*)d_in[6];
    float* out = (float*)d_out;

    unsigned short* ws = (unsigned short*)d_ws;
    unsigned short* WtS = ws;                      // 384 KB
    unsigned short* Qb = ws + 192 * 1024;          // 2 MB
    unsigned short* Kb = Qb + QTOT * 64;           // 2 MB
    unsigned short* VT = Kb + QTOT * 64;           // 2 MB  (total 6,684,672 B)

    prep_weights<<<768, 256, 0, stream>>>(Wq, Wk, Wv, WtS);
    proj_cs<<<512, 256, 0, stream>>>(emb, WtS, bq, bk, bv, Qb, Kb, VT);
    attn<<<256, 512, 0, stream>>>(Qb, Kb, VT, out);
}